// Round 10
// baseline (324.209 us; speedup 1.0000x reference)
//
#include <hip/hip_runtime.h>

// FFCoSTA: 15-step thermal recurrence (pbm + tiny MLP) over B=65536 elements,
// output = (32,B,13) x2 where slices 0..30 are broadcast copies of the input.
//
// R1:  h[64] un-chunked -> VGPR=256 + spill, 4.8 GB scratch, 4.25 ms.
// R5:  weights in LDS -> 160 us (LDS-port delivery bound, 1 wave/SIMD).
// R6/R7: weights via s_load -> 260 us (scalar-chain latency, no TLP).
// R8:  MFMA element-per-column, weights in VGPRs, copy folded -> ~95 us.
// R9-R12: copy-shape ablation (fold / issue density / address order / store
//      opcode / grid-frontier): ALL FALSIFIED — every CU-store variant
//      drains 2.2-2.4 TB/s.
// R13: role-split serialization: total ~100 us serial vs ~95 concurrent ->
//      split pinned: copy ~85-90 us (the long pole), compute ~8-10, prep ~3.
//      Also: fill's WRITE_SIZE = 4x out -> the 6.6 TB/s fill poisons the
//      WORKSPACE; fast pure-write was never demonstrated on `out` nor by
//      hipcc code. Unfalsified variables: target buffer, kernel provenance.
// R14 (this): test the runtime blit path on `out`: replace the CU copy with
//      12 hipMemcpyAsync D2D doubling copies (harness-blessed, graph-safe):
//      seed slice 0 per tensor from input, then double 1,2,4,8,15 slices.
//      Writes 211 MB via the same rocclr blit machinery as the 6.6 TB/s
//      fill; reads are LLC-warm (just-written). Compute = R8 engine verbatim
//      (slice 31). Branches: blit-fast => dur ~245-275 (CU-store path was
//      the ceiling); blit ~2.4 => dur ~295-315 (buffer-universal write
//      ceiling -> declare roofline with that arithmetic).

#define STATE 13
#define HID   64
#define PRED  32
#define NSTEP 15

typedef float    f32x4 __attribute__((ext_vector_type(4)));
typedef short    s16x8 __attribute__((ext_vector_type(8)));
typedef unsigned u32x2 __attribute__((ext_vector_type(2)));

constexpr int B      = 65536;
constexpr int B13    = B * STATE;     // 851968 floats per slice
constexpr size_t SLB = (size_t)B13 * 4;   // bytes per slice (3.4 MB)
constexpr int CBLK   = B / 64;        // 1024 compute blocks, 64 elems each

// ws byte offsets (fragment tables, 15360 B total)
constexpr int WS_W1F = 0;        // [4 tiles][64 lanes] s16x8  = 4096 B
constexpr int WS_W2F = 4096;     // [2 slices][64]      s16x8  = 2048 B
constexpr int WS_B1C = 6144;     // [4][64]             f32x4  = 4096 B
constexpr int WS_B2C = 10240;    // [64]                f32x4  = 1024 B
constexpr int WS_SK  = 11264;    // [4][64]             f32x4  = 4096 B

__device__ __forceinline__ unsigned short f2bf(float f) {
    return __builtin_bit_cast(unsigned short, (__bf16)f);
}
__device__ __forceinline__ unsigned pkbf(float lo, float hi) {
    return (unsigned)f2bf(lo) | ((unsigned)f2bf(hi) << 16);
}
__device__ __forceinline__ float bflo(unsigned u) { return __builtin_bit_cast(float, u << 16); }
__device__ __forceinline__ float bfhi(unsigned u) { return __builtin_bit_cast(float, u & 0xffff0000u); }

// x-dim layout (32): [0..12]=Tr, [13..15]=0 pad, [16..28]=Tw, [29..31]=To,d,t.
// W1 orig rows: 0-12 Tr, 13-25 Tw, 26-28 extras -> orig = nd<13 ? nd : nd-3.
__global__ __launch_bounds__(256) void ffcosta_prep(
    const float* __restrict__ W1, const float* __restrict__ b1,
    const float* __restrict__ W2, const float* __restrict__ b2,
    const float* __restrict__ k_rw, const float* __restrict__ k_ro,
    const float* __restrict__ k_wr, const float* __restrict__ k_wo,
    char* __restrict__ ws)
{
    const int tid = threadIdx.x;
    const float s = 60.0f / 3600.0f;

    // W1T A-frags: A[m=j][k=nd], lane: m=16t+(l&15), k=8*(l>>4)+r
    unsigned short* w1f = (unsigned short*)(ws + WS_W1F);
    for (int idx = tid; idx < 4*64*8; idx += 256) {
        const int t = idx >> 9, l = (idx >> 3) & 63, r = idx & 7;
        const int nd = 8*(l>>4) + r;
        const int j  = 16*t + (l & 15);
        float v = 0.0f;
        if (nd < 13)       v = W1[nd*HID + j];
        else if (nd >= 16) v = W1[(nd-3)*HID + j];
        w1f[idx] = f2bf(v);
    }
    // W2T A-frags: A[m=c][k=j], lane: c=l&15, j=32s+8*(l>>4)+r
    unsigned short* w2f = (unsigned short*)(ws + WS_W2F);
    for (int idx = tid; idx < 2*64*8; idx += 256) {
        const int sl = idx >> 9, l = (idx >> 3) & 63, r = idx & 7;
        const int j = 32*sl + 8*(l>>4) + r;
        const int c = l & 15;
        w2f[idx] = (c < STATE) ? f2bf(W2[j*STATE + c]) : (unsigned short)0;
    }
    // b1 C-frags: C row = m = 16t + 4*(l>>4) + r
    float* b1c = (float*)(ws + WS_B1C);
    for (int idx = tid; idx < 4*64*4; idx += 256) {
        const int t = idx >> 8, l = (idx >> 2) & 63, r = idx & 3;
        b1c[idx] = b1[16*t + 4*(l>>4) + r];
    }
    // b2 C-frag: row = c = 4*(l>>4) + r, pad rows 13-15 = 0
    float* b2c = (float*)(ws + WS_B2C);
    for (int idx = tid; idx < 64*4; idx += 256) {
        const int l = idx >> 2, r = idx & 3;
        const int c = 4*(l>>4) + r;
        b2c[idx] = (c < STATE) ? b2[c] : 0.0f;
    }
    // s*k per lane (state dim = 4*(l>>4)+r), pad dims -> 0 (pbm no-op on pads)
    float* sk = (float*)(ws + WS_SK);
    for (int idx = tid; idx < 4*64*4; idx += 256) {
        const int a = idx >> 8, l = (idx >> 2) & 63, r = idx & 3;
        const int c = 4*(l>>4) + r;
        const float* ka = (a==0)? k_rw : (a==1)? k_ro : (a==2)? k_wr : k_wo;
        sk[idx] = (c < STATE) ? s * ka[c] : 0.0f;
    }
}

__global__ __launch_bounds__(256) void ffcosta_compute(
    const float* __restrict__ T_room, const float* __restrict__ T_wall,
    const float* __restrict__ T_out,  const float* __restrict__ door,
    const float* __restrict__ timing,
    const char*  __restrict__ ws,
    float* __restrict__ out)
{
    // per-wave-private LDS tiles (no barriers anywhere):
    // +0:    x_hi  16 rows x 64 B   (bf16, x-dim byte = 2*nd)
    // +1024: x_lo
    // +2048: h_hi  16 rows x 128 B  (bf16, byte = 2*j)
    // +4096: h_lo      -> 6144 B per wave, 24576 per block
    __shared__ __align__(16) char smem[4 * 6144];

    float* out0 = out;                              // T_room_new
    float* out1 = out + (size_t)PRED * B13;         // T_wall_new

    const int tid  = threadIdx.x;
    const int lane = tid & 63, w = tid >> 6;
    const int el   = lane & 15, hi = lane >> 4;
    const int e    = blockIdx.x * 64 + w * 16 + el;

    // ---- invariant per-lane preloads (weights live in VGPRs) ----
    s16x8 w1a[4], w2a[2];
    f32x4 b1c[4], b2c, skrw, skro, skwr, skwo;
    #pragma unroll
    for (int t = 0; t < 4; ++t) {
        w1a[t] = *(const s16x8*)(ws + WS_W1F + (t*64 + lane)*16);
        b1c[t] = *(const f32x4*)(ws + WS_B1C + (t*64 + lane)*16);
    }
    #pragma unroll
    for (int sl = 0; sl < 2; ++sl)
        w2a[sl] = *(const s16x8*)(ws + WS_W2F + (sl*64 + lane)*16);
    b2c  = *(const f32x4*)(ws + WS_B2C + lane*16);
    skrw = *(const f32x4*)(ws + WS_SK +        lane*16);
    skro = *(const f32x4*)(ws + WS_SK + 1024 + lane*16);
    skwr = *(const f32x4*)(ws + WS_SK + 2048 + lane*16);
    skwo = *(const f32x4*)(ws + WS_SK + 3072 + lane*16);

    // ---- state init: lane holds state dims 4*hi + r for element e ----
    // hi==3 lanes: Tr[0]=Tr[12], Tw[0]=Tw[12], Tw[1..3]=To,d,t (x dims 29-31);
    // their sk pads are 0 so pbm passes them through untouched.
    const int off4 = (hi < 3) ? 4*hi : 9;   // hi=3 loads dims 9..12, uses .w
    f32x4 vr, vw;
    __builtin_memcpy(&vr, T_room + e*STATE + off4, 16);
    __builtin_memcpy(&vw, T_wall + e*STATE + off4, 16);
    const float To = T_out [e*PRED + (PRED-1)];
    const float dv = door  [e*PRED + (PRED-1)];
    const float tv = timing[e*PRED + (PRED-1)];
    float Tr[4], Tw[4];
    if (hi < 3) {
        Tr[0]=vr[0]; Tr[1]=vr[1]; Tr[2]=vr[2]; Tr[3]=vr[3];
        Tw[0]=vw[0]; Tw[1]=vw[1]; Tw[2]=vw[2]; Tw[3]=vw[3];
    } else {
        Tr[0]=vr[3]; Tr[1]=0.0f; Tr[2]=0.0f; Tr[3]=0.0f;
        Tw[0]=vw[3]; Tw[1]=To;   Tw[2]=dv;   Tw[3]=tv;
    }

    // ---- LDS offsets (XOR-swizzled, step-invariant) ----
    const int wb = w * 6144;
    const int xk = (el & 3) << 4;          // x-tile row = 64 B
    const int hk = (el & 7) << 4;          // h-tile row = 128 B
    const int a_xw_tr = wb + el*64 + (( 8*hi) ^ xk);   // Tr dims -> bytes 8hi+2r
    const int a_xw_tw = wb + el*64 + ((32 + 8*hi) ^ xk);
    const int a_xr    = wb + el*64 + ((16*hi) ^ xk);   // k = 8hi..8hi+7
    int a_hw[4], a_hr[2];
    #pragma unroll
    for (int t = 0; t < 4; ++t) a_hw[t] = wb + 2048 + el*128 + ((32*t + 8*hi) ^ hk);
    #pragma unroll
    for (int sl = 0; sl < 2; ++sl) a_hr[sl] = wb + 2048 + el*128 + ((64*sl + 16*hi) ^ hk);

    const float s001 = (60.0f/3600.0f) * 0.01f;

    #pragma unroll 1
    for (int n = 0; n < NSTEP; ++n) {
        // pbm, exact fp32 in registers (pad rows: sk=0 -> identity)
        #pragma unroll
        for (int r = 0; r < 4; ++r) {
            const float dA = Tw[r] - Tr[r];
            const float dB = To    - Tr[r];
            const float dC = To    - Tw[r];
            Tr[r] = fmaf(dB, skro[r], fmaf(dA, skrw[r], Tr[r]));
            Tw[r] = fmaf(dC, skwo[r], fmaf(-dA, skwr[r], Tw[r]));
        }

        // pack x_hi + residual x_lo, write (2+2 b64)
        const unsigned tr01 = pkbf(Tr[0], Tr[1]), tr23 = pkbf(Tr[2], Tr[3]);
        const unsigned tw01 = pkbf(Tw[0], Tw[1]), tw23 = pkbf(Tw[2], Tw[3]);
        u32x2 v;
        v[0]=tr01; v[1]=tr23; *(u32x2*)(smem + a_xw_tr) = v;
        v[0]=tw01; v[1]=tw23; *(u32x2*)(smem + a_xw_tw) = v;
        v[0]=pkbf(Tr[0]-bflo(tr01), Tr[1]-bfhi(tr01));
        v[1]=pkbf(Tr[2]-bflo(tr23), Tr[3]-bfhi(tr23));
        *(u32x2*)(smem + a_xw_tr + 1024) = v;
        v[0]=pkbf(Tw[0]-bflo(tw01), Tw[1]-bfhi(tw01));
        v[1]=pkbf(Tw[2]-bflo(tw23), Tw[3]-bfhi(tw23));
        *(u32x2*)(smem + a_xw_tw + 1024) = v;

        // B-frags for layer 1 (same-wave lgkmcnt ordering, no barrier)
        const s16x8 xbh = *(const s16x8*)(smem + a_xr);
        const s16x8 xbl = *(const s16x8*)(smem + a_xr + 1024);

        // layer 1: hT[j][e] = b1 + W1T@x_hi + W1T@x_lo
        f32x4 acc[4];
        #pragma unroll
        for (int t = 0; t < 4; ++t) {
            acc[t] = __builtin_amdgcn_mfma_f32_16x16x32_bf16(w1a[t], xbh, b1c[t], 0, 0, 0);
            acc[t] = __builtin_amdgcn_mfma_f32_16x16x32_bf16(w1a[t], xbl, acc[t], 0, 0, 0);
        }

        // relu, pack h_hi + h_lo, write (4+4 b64)
        #pragma unroll
        for (int t = 0; t < 4; ++t) {
            const float h0 = fmaxf(acc[t][0], 0.0f), h1 = fmaxf(acc[t][1], 0.0f);
            const float h2 = fmaxf(acc[t][2], 0.0f), h3 = fmaxf(acc[t][3], 0.0f);
            const unsigned p01 = pkbf(h0, h1), p23 = pkbf(h2, h3);
            u32x2 hv; hv[0]=p01; hv[1]=p23;
            *(u32x2*)(smem + a_hw[t]) = hv;
            hv[0] = pkbf(h0-bflo(p01), h1-bfhi(p01));
            hv[1] = pkbf(h2-bflo(p23), h3-bfhi(p23));
            *(u32x2*)(smem + a_hw[t] + 2048) = hv;
        }

        const s16x8 hb0 = *(const s16x8*)(smem + a_hr[0]);
        const s16x8 hb1 = *(const s16x8*)(smem + a_hr[1]);
        const s16x8 hl0 = *(const s16x8*)(smem + a_hr[0] + 2048);
        const s16x8 hl1 = *(const s16x8*)(smem + a_hr[1] + 2048);

        // layer 2: srcT[c][e] = b2 + W2T@h_hi + W2T@h_lo  (pad rows -> 0)
        f32x4 sv = b2c;
        sv = __builtin_amdgcn_mfma_f32_16x16x32_bf16(w2a[0], hb0, sv, 0, 0, 0);
        sv = __builtin_amdgcn_mfma_f32_16x16x32_bf16(w2a[1], hb1, sv, 0, 0, 0);
        sv = __builtin_amdgcn_mfma_f32_16x16x32_bf16(w2a[0], hl0, sv, 0, 0, 0);
        sv = __builtin_amdgcn_mfma_f32_16x16x32_bf16(w2a[1], hl1, sv, 0, 0, 0);

        // state update: Tr += s*0.01*src_raw (pad rows get +0)
        #pragma unroll
        for (int r = 0; r < 4; ++r) Tr[r] = fmaf(sv[r], s001, Tr[r]);
    }

    // final slice 31: lane stores dims 4hi..4hi+3 (hi=3: dim 12 only)
    float* p0 = out0 + (size_t)(PRED-1) * B13 + e*STATE;
    float* p1 = p0 + (size_t)PRED * B13;
    if (hi < 3) {
        f32x4 s0, s1;
        s0[0]=Tr[0]; s0[1]=Tr[1]; s0[2]=Tr[2]; s0[3]=Tr[3];
        s1[0]=Tw[0]; s1[1]=Tw[1]; s1[2]=Tw[2]; s1[3]=Tw[3];
        __builtin_memcpy(p0 + 4*hi, &s0, 16);
        __builtin_memcpy(p1 + 4*hi, &s1, 16);
    } else {
        p0[12] = Tr[0];
        p1[12] = Tw[0];
    }
}

extern "C" void kernel_launch(void* const* d_in, const int* in_sizes, int n_in,
                              void* d_out, int out_size, void* d_ws, size_t ws_size,
                              hipStream_t stream) {
    const float* T_room = (const float*)d_in[0];
    const float* T_wall = (const float*)d_in[1];
    const float* T_out  = (const float*)d_in[2];
    const float* door   = (const float*)d_in[3];
    const float* timing = (const float*)d_in[4];
    const float* k_rw   = (const float*)d_in[5];
    const float* k_ro   = (const float*)d_in[6];
    const float* k_wr   = (const float*)d_in[7];
    const float* k_wo   = (const float*)d_in[8];
    const float* W1     = (const float*)d_in[9];
    const float* b1     = (const float*)d_in[10];
    const float* W2     = (const float*)d_in[11];
    const float* b2     = (const float*)d_in[12];
    float* out = (float*)d_out;
    char*  ws  = (char*)d_ws;

    ffcosta_prep<<<1, 256, 0, stream>>>(W1, b1, W2, b2, k_rw, k_ro, k_wr, k_wo, ws);
    ffcosta_compute<<<CBLK, 256, 0, stream>>>(
        T_room, T_wall, T_out, door, timing, ws, out);

    // slices 0..30 of both tensors via runtime blit (doubling):
    // seed slice 0 from input, then 1,2,4,8,15-slice self-copies.
    float* out0 = out;
    float* out1 = out + (size_t)PRED * B13;
    hipMemcpyAsync(out0, T_room, SLB, hipMemcpyDeviceToDevice, stream);
    hipMemcpyAsync(out1, T_wall, SLB, hipMemcpyDeviceToDevice, stream);
    hipMemcpyAsync(out0 +  1*(size_t)B13, out0,  1*SLB, hipMemcpyDeviceToDevice, stream);
    hipMemcpyAsync(out1 +  1*(size_t)B13, out1,  1*SLB, hipMemcpyDeviceToDevice, stream);
    hipMemcpyAsync(out0 +  2*(size_t)B13, out0,  2*SLB, hipMemcpyDeviceToDevice, stream);
    hipMemcpyAsync(out1 +  2*(size_t)B13, out1,  2*SLB, hipMemcpyDeviceToDevice, stream);
    hipMemcpyAsync(out0 +  4*(size_t)B13, out0,  4*SLB, hipMemcpyDeviceToDevice, stream);
    hipMemcpyAsync(out1 +  4*(size_t)B13, out1,  4*SLB, hipMemcpyDeviceToDevice, stream);
    hipMemcpyAsync(out0 +  8*(size_t)B13, out0,  8*SLB, hipMemcpyDeviceToDevice, stream);
    hipMemcpyAsync(out1 +  8*(size_t)B13, out1,  8*SLB, hipMemcpyDeviceToDevice, stream);
    hipMemcpyAsync(out0 + 16*(size_t)B13, out0, 15*SLB, hipMemcpyDeviceToDevice, stream);
    hipMemcpyAsync(out1 + 16*(size_t)B13, out1, 15*SLB, hipMemcpyDeviceToDevice, stream);
}

// Round 11
// 286.858 us; speedup vs baseline: 1.1302x; 1.1302x over previous
//
#include <hip/hip_runtime.h>

// FFCoSTA: 15-step thermal recurrence (pbm + tiny MLP) over B=65536 elements,
// output = (32,B,13) x2 where slices 0..30 are broadcast copies of the input.
//
// R1:  h[64] un-chunked -> VGPR=256 + spill, 4.8 GB scratch, 4.25 ms.
// R5:  weights in LDS -> 160 us (LDS-port delivery bound, 1 wave/SIMD).
// R6/R7: weights via s_load -> 260 us (scalar-chain latency, no TLP).
// R8:  MFMA element-per-column, weights in VGPRs, copy folded -> ~95 us GPU
//      (dur 287.8 = best; harness constant ~193 us: ws-fill 131 us + poison
//      + launch overhead, fixed).
// R9-R12: copy-shape ablation: issue density / address order / store opcode
//      (nt vs plain) / grid-frontier fill-clone — ALL FALSIFIED, every CU
//      variant drains `out` at 2.2-2.4 TB/s.
// R13: role-split serialization pins the split: copy ~85-90 us (long pole),
//      compute ~8-10 us, prep ~3 us.
// R14: runtime blit (hipMemcpyAsync doubling) on `out`: ALSO ~2 TB/s.
//      CONCLUSION: the ~2.4 TB/s write ceiling is a property of the `out`
//      BUFFER (likely host-visible/fine-grained allocation), not of any
//      store path — CU stores, nt, plain, and rocclr blit all hit it; the
//      6.6 TB/s fill targets the workspace, not out.
//      Roofline: 218 MB mandatory writes / 2.4 TB/s ~ 90 us; R8 runs ~95 us
//      with compute and reads fully hidden -> within ~5% of the floor.
// R15 (this): revert to the best-measured configuration (R8 verbatim).
//      Convergence round; expect dur_us ~ 288 +- 6, then declare roofline.

#define STATE 13
#define HID   64
#define PRED  32
#define NSTEP 15

typedef float    f32x4 __attribute__((ext_vector_type(4)));
typedef short    s16x8 __attribute__((ext_vector_type(8)));
typedef unsigned u32x2 __attribute__((ext_vector_type(2)));
typedef float    vfloat4 __attribute__((ext_vector_type(4)));

constexpr int B      = 65536;
constexpr int B13    = B * STATE;     // 851968 floats per slice
constexpr int B13_4  = B13 / 4;       // 212992 float4s per slice
constexpr int CBLK   = B / 64;        // 1024 blocks, 64 elems each

// ws byte offsets (fragment tables, 15360 B total)
constexpr int WS_W1F = 0;        // [4 tiles][64 lanes] s16x8  = 4096 B
constexpr int WS_W2F = 4096;     // [2 slices][64]      s16x8  = 2048 B
constexpr int WS_B1C = 6144;     // [4][64]             f32x4  = 4096 B
constexpr int WS_B2C = 10240;    // [64]                f32x4  = 1024 B
constexpr int WS_SK  = 11264;    // [4][64]             f32x4  = 4096 B

__device__ __forceinline__ unsigned short f2bf(float f) {
    return __builtin_bit_cast(unsigned short, (__bf16)f);
}
__device__ __forceinline__ unsigned pkbf(float lo, float hi) {
    return (unsigned)f2bf(lo) | ((unsigned)f2bf(hi) << 16);
}
__device__ __forceinline__ float bflo(unsigned u) { return __builtin_bit_cast(float, u << 16); }
__device__ __forceinline__ float bfhi(unsigned u) { return __builtin_bit_cast(float, u & 0xffff0000u); }

// x-dim layout (32): [0..12]=Tr, [13..15]=0 pad, [16..28]=Tw, [29..31]=To,d,t.
// W1 orig rows: 0-12 Tr, 13-25 Tw, 26-28 extras -> orig = nd<13 ? nd : nd-3.
__global__ __launch_bounds__(256) void ffcosta_prep(
    const float* __restrict__ W1, const float* __restrict__ b1,
    const float* __restrict__ W2, const float* __restrict__ b2,
    const float* __restrict__ k_rw, const float* __restrict__ k_ro,
    const float* __restrict__ k_wr, const float* __restrict__ k_wo,
    char* __restrict__ ws)
{
    const int tid = threadIdx.x;
    const float s = 60.0f / 3600.0f;

    // W1T A-frags: A[m=j][k=nd], lane: m=16t+(l&15), k=8*(l>>4)+r
    unsigned short* w1f = (unsigned short*)(ws + WS_W1F);
    for (int idx = tid; idx < 4*64*8; idx += 256) {
        const int t = idx >> 9, l = (idx >> 3) & 63, r = idx & 7;
        const int nd = 8*(l>>4) + r;
        const int j  = 16*t + (l & 15);
        float v = 0.0f;
        if (nd < 13)       v = W1[nd*HID + j];
        else if (nd >= 16) v = W1[(nd-3)*HID + j];
        w1f[idx] = f2bf(v);
    }
    // W2T A-frags: A[m=c][k=j], lane: c=l&15, j=32s+8*(l>>4)+r
    unsigned short* w2f = (unsigned short*)(ws + WS_W2F);
    for (int idx = tid; idx < 2*64*8; idx += 256) {
        const int sl = idx >> 9, l = (idx >> 3) & 63, r = idx & 7;
        const int j = 32*sl + 8*(l>>4) + r;
        const int c = l & 15;
        w2f[idx] = (c < STATE) ? f2bf(W2[j*STATE + c]) : (unsigned short)0;
    }
    // b1 C-frags: C row = m = 16t + 4*(l>>4) + r
    float* b1c = (float*)(ws + WS_B1C);
    for (int idx = tid; idx < 4*64*4; idx += 256) {
        const int t = idx >> 8, l = (idx >> 2) & 63, r = idx & 3;
        b1c[idx] = b1[16*t + 4*(l>>4) + r];
    }
    // b2 C-frag: row = c = 4*(l>>4) + r, pad rows 13-15 = 0
    float* b2c = (float*)(ws + WS_B2C);
    for (int idx = tid; idx < 64*4; idx += 256) {
        const int l = idx >> 2, r = idx & 3;
        const int c = 4*(l>>4) + r;
        b2c[idx] = (c < STATE) ? b2[c] : 0.0f;
    }
    // s*k per lane (state dim = 4*(l>>4)+r), pad dims -> 0 (pbm no-op on pads)
    float* sk = (float*)(ws + WS_SK);
    for (int idx = tid; idx < 4*64*4; idx += 256) {
        const int a = idx >> 8, l = (idx >> 2) & 63, r = idx & 3;
        const int c = 4*(l>>4) + r;
        const float* ka = (a==0)? k_rw : (a==1)? k_ro : (a==2)? k_wr : k_wo;
        sk[idx] = (c < STATE) ? s * ka[c] : 0.0f;
    }
}

__global__ __launch_bounds__(256) void ffcosta_kernel(
    const float* __restrict__ T_room, const float* __restrict__ T_wall,
    const float* __restrict__ T_out,  const float* __restrict__ door,
    const float* __restrict__ timing,
    const char*  __restrict__ ws,
    float* __restrict__ out)
{
    // per-wave-private LDS tiles (no barriers anywhere):
    // +0:    x_hi  16 rows x 64 B   (bf16, x-dim byte = 2*nd)
    // +1024: x_lo
    // +2048: h_hi  16 rows x 128 B  (bf16, byte = 2*j)
    // +4096: h_lo      -> 6144 B per wave, 24576 per block
    __shared__ __align__(16) char smem[4 * 6144];

    const int tid  = threadIdx.x;
    const int lane = tid & 63, w = tid >> 6;
    const int el   = lane & 15, hi = lane >> 4;
    const int e    = blockIdx.x * 64 + w * 16 + el;

    // ---- invariant per-lane preloads (weights live in VGPRs) ----
    s16x8 w1a[4], w2a[2];
    f32x4 b1c[4], b2c, skrw, skro, skwr, skwo;
    #pragma unroll
    for (int t = 0; t < 4; ++t) {
        w1a[t] = *(const s16x8*)(ws + WS_W1F + (t*64 + lane)*16);
        b1c[t] = *(const f32x4*)(ws + WS_B1C + (t*64 + lane)*16);
    }
    #pragma unroll
    for (int sl = 0; sl < 2; ++sl)
        w2a[sl] = *(const s16x8*)(ws + WS_W2F + (sl*64 + lane)*16);
    b2c  = *(const f32x4*)(ws + WS_B2C + lane*16);
    skrw = *(const f32x4*)(ws + WS_SK +        lane*16);
    skro = *(const f32x4*)(ws + WS_SK + 1024 + lane*16);
    skwr = *(const f32x4*)(ws + WS_SK + 2048 + lane*16);
    skwo = *(const f32x4*)(ws + WS_SK + 3072 + lane*16);

    // ---- state init: lane holds state dims 4*hi + r for element e ----
    // hi==3 lanes: Tr[0]=Tr[12], Tw[0]=Tw[12], Tw[1..3]=To,d,t (x dims 29-31);
    // their sk pads are 0 so pbm passes them through untouched.
    const int off4 = (hi < 3) ? 4*hi : 9;   // hi=3 loads dims 9..12, uses .w
    f32x4 vr, vw;
    __builtin_memcpy(&vr, T_room + e*STATE + off4, 16);
    __builtin_memcpy(&vw, T_wall + e*STATE + off4, 16);
    const float To = T_out [e*PRED + (PRED-1)];
    const float dv = door  [e*PRED + (PRED-1)];
    const float tv = timing[e*PRED + (PRED-1)];
    float Tr[4], Tw[4];
    if (hi < 3) {
        Tr[0]=vr[0]; Tr[1]=vr[1]; Tr[2]=vr[2]; Tr[3]=vr[3];
        Tw[0]=vw[0]; Tw[1]=vw[1]; Tw[2]=vw[2]; Tw[3]=vw[3];
    } else {
        Tr[0]=vr[3]; Tr[1]=0.0f; Tr[2]=0.0f; Tr[3]=0.0f;
        Tw[0]=vw[3]; Tw[1]=To;   Tw[2]=dv;   Tw[3]=tv;
    }

    // ---- broadcast-copy role (folded): 1 float4 per thread per slice ----
    const int  cf = blockIdx.x * 256 + tid;
    const bool cvalid = cf < B13_4;
    vfloat4 crm = {0,0,0,0}, cwl = {0,0,0,0};
    if (cvalid) {
        crm = ((const vfloat4*)T_room)[cf];
        cwl = ((const vfloat4*)T_wall)[cf];
    }
    vfloat4* out0_4 = (vfloat4*)out;
    vfloat4* out1_4 = (vfloat4*)(out + (size_t)PRED * B13);

    // ---- LDS offsets (XOR-swizzled, step-invariant) ----
    const int wb = w * 6144;
    const int xk = (el & 3) << 4;          // x-tile row = 64 B
    const int hk = (el & 7) << 4;          // h-tile row = 128 B
    const int a_xw_tr = wb + el*64 + (( 8*hi) ^ xk);   // Tr dims -> bytes 8hi+2r
    const int a_xw_tw = wb + el*64 + ((32 + 8*hi) ^ xk);
    const int a_xr    = wb + el*64 + ((16*hi) ^ xk);   // k = 8hi..8hi+7
    int a_hw[4], a_hr[2];
    #pragma unroll
    for (int t = 0; t < 4; ++t) a_hw[t] = wb + 2048 + el*128 + ((32*t + 8*hi) ^ hk);
    #pragma unroll
    for (int sl = 0; sl < 2; ++sl) a_hr[sl] = wb + 2048 + el*128 + ((64*sl + 16*hi) ^ hk);

    const float s001 = (60.0f/3600.0f) * 0.01f;

    #pragma unroll 1
    for (int n = 0; n < NSTEP; ++n) {
        // copy stores for slices 2n, 2n+1 (fire-and-forget, drains under compute)
        if (cvalid) {
            const int i0 = (2*n) * B13_4 + cf;
            __builtin_nontemporal_store(crm, out0_4 + i0);
            __builtin_nontemporal_store(crm, out0_4 + i0 + B13_4);
            __builtin_nontemporal_store(cwl, out1_4 + i0);
            __builtin_nontemporal_store(cwl, out1_4 + i0 + B13_4);
        }

        // pbm, exact fp32 in registers (pad rows: sk=0 -> identity)
        #pragma unroll
        for (int r = 0; r < 4; ++r) {
            const float dA = Tw[r] - Tr[r];
            const float dB = To    - Tr[r];
            const float dC = To    - Tw[r];
            Tr[r] = fmaf(dB, skro[r], fmaf(dA, skrw[r], Tr[r]));
            Tw[r] = fmaf(dC, skwo[r], fmaf(-dA, skwr[r], Tw[r]));
        }

        // pack x_hi + residual x_lo, write (2+2 b64)
        const unsigned tr01 = pkbf(Tr[0], Tr[1]), tr23 = pkbf(Tr[2], Tr[3]);
        const unsigned tw01 = pkbf(Tw[0], Tw[1]), tw23 = pkbf(Tw[2], Tw[3]);
        u32x2 v;
        v[0]=tr01; v[1]=tr23; *(u32x2*)(smem + a_xw_tr) = v;
        v[0]=tw01; v[1]=tw23; *(u32x2*)(smem + a_xw_tw) = v;
        v[0]=pkbf(Tr[0]-bflo(tr01), Tr[1]-bfhi(tr01));
        v[1]=pkbf(Tr[2]-bflo(tr23), Tr[3]-bfhi(tr23));
        *(u32x2*)(smem + a_xw_tr + 1024) = v;
        v[0]=pkbf(Tw[0]-bflo(tw01), Tw[1]-bfhi(tw01));
        v[1]=pkbf(Tw[2]-bflo(tw23), Tw[3]-bfhi(tw23));
        *(u32x2*)(smem + a_xw_tw + 1024) = v;

        // B-frags for layer 1 (same-wave lgkmcnt ordering, no barrier)
        const s16x8 xbh = *(const s16x8*)(smem + a_xr);
        const s16x8 xbl = *(const s16x8*)(smem + a_xr + 1024);

        // layer 1: hT[j][e] = b1 + W1T@x_hi + W1T@x_lo
        f32x4 acc[4];
        #pragma unroll
        for (int t = 0; t < 4; ++t) {
            acc[t] = __builtin_amdgcn_mfma_f32_16x16x32_bf16(w1a[t], xbh, b1c[t], 0, 0, 0);
            acc[t] = __builtin_amdgcn_mfma_f32_16x16x32_bf16(w1a[t], xbl, acc[t], 0, 0, 0);
        }

        // relu, pack h_hi + h_lo, write (4+4 b64)
        #pragma unroll
        for (int t = 0; t < 4; ++t) {
            const float h0 = fmaxf(acc[t][0], 0.0f), h1 = fmaxf(acc[t][1], 0.0f);
            const float h2 = fmaxf(acc[t][2], 0.0f), h3 = fmaxf(acc[t][3], 0.0f);
            const unsigned p01 = pkbf(h0, h1), p23 = pkbf(h2, h3);
            u32x2 hv; hv[0]=p01; hv[1]=p23;
            *(u32x2*)(smem + a_hw[t]) = hv;
            hv[0] = pkbf(h0-bflo(p01), h1-bfhi(p01));
            hv[1] = pkbf(h2-bflo(p23), h3-bfhi(p23));
            *(u32x2*)(smem + a_hw[t] + 2048) = hv;
        }

        const s16x8 hb0 = *(const s16x8*)(smem + a_hr[0]);
        const s16x8 hb1 = *(const s16x8*)(smem + a_hr[1]);
        const s16x8 hl0 = *(const s16x8*)(smem + a_hr[0] + 2048);
        const s16x8 hl1 = *(const s16x8*)(smem + a_hr[1] + 2048);

        // layer 2: srcT[c][e] = b2 + W2T@h_hi + W2T@h_lo  (pad rows -> 0)
        f32x4 sv = b2c;
        sv = __builtin_amdgcn_mfma_f32_16x16x32_bf16(w2a[0], hb0, sv, 0, 0, 0);
        sv = __builtin_amdgcn_mfma_f32_16x16x32_bf16(w2a[1], hb1, sv, 0, 0, 0);
        sv = __builtin_amdgcn_mfma_f32_16x16x32_bf16(w2a[0], hl0, sv, 0, 0, 0);
        sv = __builtin_amdgcn_mfma_f32_16x16x32_bf16(w2a[1], hl1, sv, 0, 0, 0);

        // state update: Tr += s*0.01*src_raw (pad rows get +0)
        #pragma unroll
        for (int r = 0; r < 4; ++r) Tr[r] = fmaf(sv[r], s001, Tr[r]);
    }

    // copy slice 30
    if (cvalid) {
        const int i0 = 30 * B13_4 + cf;
        __builtin_nontemporal_store(crm, out0_4 + i0);
        __builtin_nontemporal_store(cwl, out1_4 + i0);
    }

    // final slice 31: lane stores dims 4hi..4hi+3 (hi=3: dim 12 only)
    float* p0 = out + (size_t)(PRED-1) * B13 + e*STATE;
    float* p1 = p0 + (size_t)PRED * B13;
    if (hi < 3) {
        f32x4 s0, s1;
        s0[0]=Tr[0]; s0[1]=Tr[1]; s0[2]=Tr[2]; s0[3]=Tr[3];
        s1[0]=Tw[0]; s1[1]=Tw[1]; s1[2]=Tw[2]; s1[3]=Tw[3];
        __builtin_memcpy(p0 + 4*hi, &s0, 16);
        __builtin_memcpy(p1 + 4*hi, &s1, 16);
    } else {
        p0[12] = Tr[0];
        p1[12] = Tw[0];
    }
}

extern "C" void kernel_launch(void* const* d_in, const int* in_sizes, int n_in,
                              void* d_out, int out_size, void* d_ws, size_t ws_size,
                              hipStream_t stream) {
    const float* T_room = (const float*)d_in[0];
    const float* T_wall = (const float*)d_in[1];
    const float* T_out  = (const float*)d_in[2];
    const float* door   = (const float*)d_in[3];
    const float* timing = (const float*)d_in[4];
    const float* k_rw   = (const float*)d_in[5];
    const float* k_ro   = (const float*)d_in[6];
    const float* k_wr   = (const float*)d_in[7];
    const float* k_wo   = (const float*)d_in[8];
    const float* W1     = (const float*)d_in[9];
    const float* b1     = (const float*)d_in[10];
    const float* W2     = (const float*)d_in[11];
    const float* b2     = (const float*)d_in[12];
    float* out = (float*)d_out;
    char*  ws  = (char*)d_ws;

    ffcosta_prep<<<1, 256, 0, stream>>>(W1, b1, W2, b2, k_rw, k_ro, k_wr, k_wo, ws);
    ffcosta_kernel<<<CBLK, 256, 0, stream>>>(
        T_room, T_wall, T_out, door, timing, ws, out);
}